// Round 1
// baseline (1755.949 us; speedup 1.0000x reference)
//
#include <hip/hip_runtime.h>
#include <hip/hip_bf16.h>

// EdgeModel: out = relu(concat(src,dest,edge_attr,u[batch]) @ W1 + b1) @ W2 + b2
// E=500000, F_IN=35 (pad->64), H=512, OUT=512.
// Persistent pipelined version: 512 blocks grid-stride over 64-edge tiles;
// next tile's gather is issued via global_load_lds right after the hs barrier
// and lands under the 16-kstep W2t loop (T14 issue-early / consume-late).

#define E_TOTAL   500000
#define H_SZ      512
#define OUT_SZ    512
#define K1        64        // layer-1 K padded 35 -> 64 (zeros both sides)
#define MT        64        // edges per tile
#define NT        ((E_TOTAL + MT - 1) / MT)   // 7813 tiles
#define NB        512       // persistent grid: 2 blocks/CU * 256 CU

typedef __attribute__((ext_vector_type(8))) short bf16x8;   // 8 bf16 = 4 VGPRs
typedef __attribute__((ext_vector_type(4))) float f32x4;    // MFMA 16x16 acc

union V8 { bf16x8 v; unsigned short s[8]; };

static __device__ __forceinline__ unsigned short f2b(float f) {
    __hip_bfloat16 h = __float2bfloat16(f);   // RNE
    return *reinterpret_cast<unsigned short*>(&h);
}

// h tile [64][512] bf16, XOR-swizzled 16B units: m-strided b128 reads 2-way (free).
static __device__ __forceinline__ int hidx(int m, int k) {
    int ku = (k >> 3) ^ (m & 7);
    return (m << 9) + (ku << 3) + (k & 7);
}

// async global->LDS, 4B per lane; LDS dest = uniform base + lane*4
static __device__ __forceinline__ void gl_lds4(const float* g, float* lds) {
    __builtin_amdgcn_global_load_lds(
        (const __attribute__((address_space(1))) void*)g,
        (__attribute__((address_space(3))) void*)lds, 4, 0, 0);
}

// ---- prep: bf16 weight repack into ws + one zero word ----
__global__ __launch_bounds__(256) void prep_weights(
        const float* __restrict__ W1, const float* __restrict__ W2,
        unsigned short* __restrict__ W2t, unsigned short* __restrict__ W1t,
        float* __restrict__ zw) {
    int t = blockIdx.x * 256 + threadIdx.x;
    if (t == 0) zw[0] = 0.0f;                   // zero source for K-pad gathers
    const int total2 = H_SZ * OUT_SZ;           // 262144
    if (t < total2) {
        int k = t >> 9, n = t & 511;            // coalesced read over n
        W2t[n * H_SZ + k] = f2b(W2[k * OUT_SZ + n]);
    } else {
        int t1 = t - total2;
        if (t1 < K1 * 512) {                    // 32768
            int k = t1 >> 9, n = t1 & 511;
            float v = (k < 35) ? W1[k * H_SZ + n] : 0.0f;
            W1t[n * K1 + k] = f2b(v);
        }
    }
}

__global__ __launch_bounds__(512, 4) void edge_mlp(
        const float* __restrict__ gsrc, const float* __restrict__ gdst,
        const float* __restrict__ gea,  const float* __restrict__ gu,
        const int* __restrict__ gbatch,
        const float* __restrict__ b1,   const float* __restrict__ b2,
        const unsigned short* __restrict__ W1t,
        const unsigned short* __restrict__ W2t,
        const float* __restrict__ zw,
        float* __restrict__ out) {

    __shared__ unsigned short hs[MT * 512];   // 64 KB h tile
    __shared__ float xs[5 * 512];             // 10 KB x tile: [fb][edge][8] f32

    const int tid  = threadIdx.x;
    const int l    = tid & 63;
    const int w    = tid >> 6;                // wave 0..7, owns cols [w*64, w*64+64)
    const int l15  = l & 15;
    const int quad = l >> 4;

    // staging lane mapping: wave w stages edges [w*8, w*8+8);
    // lane covers edge w*8+(l>>3), feature fb*8+(l&7)  -> LDS linear in lane
    const int se  = (w << 3) + (l >> 3);
    const int sc7 = l & 7;

    // biases cached once per block (lane's 4 cols)
    float b1r[4], b2r[4];
    #pragma unroll
    for (int ni = 0; ni < 4; ++ni) {
        const int col = (w << 6) + (ni << 4) + l15;
        b1r[ni] = b1[col];
        b2r[ni] = b2[col];
    }

    const unsigned short* w2p = W2t + ((w << 6) + l15) * H_SZ + (quad << 3);

    int t = blockIdx.x;

    // ---- prologue: stage tile t (5 feature-blocks per wave) ----
    {
        const int e  = min(t * MT + se, E_TOTAL - 1);
        const int bl = gbatch[e] & 1023;
        #pragma unroll
        for (int fb = 0; fb < 5; ++fb) {
            const int c = (fb << 3) + sc7;
            const float* g =
                (c < 9)   ? gsrc + (size_t)e * 9 + c :
                (c < 18)  ? gdst + (size_t)e * 9 + (c - 9) :
                (c == 18) ? gea + e :
                (c < 35)  ? gu + (bl << 4) + (c - 19) :
                            zw;                           // K-pad -> zero word
            gl_lds4(g, &xs[(fb << 9) + (w << 6)]);
        }
    }

    for (; t < NT; t += NB) {
        // ensure this wave's stage loads (and prev stores) retired, then barrier
        asm volatile("s_waitcnt vmcnt(0)" ::: "memory");
        __syncthreads();                       // xs(t) ready for all waves

        // prefetch next tile's batch early (used at stage-issue below)
        const int tn = t + NB;
        const bool have_next = (tn < NT);
        int e_n = 0, bl_n = 0;
        if (have_next) {
            e_n  = min(tn * MT + se, E_TOTAL - 1);
            bl_n = gbatch[e_n] & 1023;
        }

        // ---- layer 1: h[0:64, w*64:+64] = x[64,64] @ W1t^T, 2 ksteps ----
        f32x4 acc[4][4];
        #pragma unroll
        for (int mi = 0; mi < 4; ++mi)
            #pragma unroll
            for (int ni = 0; ni < 4; ++ni)
                acc[mi][ni] = (f32x4){0.f, 0.f, 0.f, 0.f};

        #pragma unroll
        for (int ks = 0; ks < 2; ++ks) {
            bf16x8 afr[4], bfr[4];
            const int k0 = (ks << 5) + (quad << 3);
            const int fb = k0 >> 3;            // ks0: 0..3 ; ks1 quad0: 4
            #pragma unroll
            for (int mi = 0; mi < 4; ++mi) {
                V8 a;
                if (ks == 0 || quad == 0) {    // ks1 quads1-3 cover k>=40: all zero
                    const float* p = &xs[(fb << 9) + (((mi << 4) + l15) << 3)];
                    const f32x4 lo = *reinterpret_cast<const f32x4*>(p);
                    const f32x4 hi = *reinterpret_cast<const f32x4*>(p + 4);
                    #pragma unroll
                    for (int j = 0; j < 4; ++j) {
                        a.s[j]     = f2b(lo[j]);
                        a.s[4 + j] = f2b(hi[j]);
                    }
                } else {
                    #pragma unroll
                    for (int j = 0; j < 8; ++j) a.s[j] = 0;
                }
                afr[mi] = a.v;
            }
            #pragma unroll
            for (int ni = 0; ni < 4; ++ni)
                bfr[ni] = *reinterpret_cast<const bf16x8*>(
                    &W1t[((w << 6) + (ni << 4) + l15) * K1 + k0]);
            #pragma unroll
            for (int mi = 0; mi < 4; ++mi)
                #pragma unroll
                for (int ni = 0; ni < 4; ++ni)
                    acc[mi][ni] = __builtin_amdgcn_mfma_f32_16x16x32_bf16(
                        afr[mi], bfr[ni], acc[mi][ni], 0, 0, 0);
        }

        // ---- bias + relu -> bf16 h tile in LDS ----
        #pragma unroll
        for (int ni = 0; ni < 4; ++ni) {
            const int col = (w << 6) + (ni << 4) + l15;
            #pragma unroll
            for (int mi = 0; mi < 4; ++mi)
                #pragma unroll
                for (int r = 0; r < 4; ++r) {
                    const int row = (mi << 4) + (quad << 2) + r;
                    const float v = acc[mi][ni][r] + b1r[ni];
                    hs[hidx(row, col)] = f2b(v > 0.f ? v : 0.f);
                }
        }
        __syncthreads();   // hs ready; all xs(t) reads complete

        // ---- issue next tile's gather; lands under the 16-kstep loop ----
        if (have_next) {
            #pragma unroll
            for (int fb = 0; fb < 5; ++fb) {
                const int c = (fb << 3) + sc7;
                const float* g =
                    (c < 9)   ? gsrc + (size_t)e_n * 9 + c :
                    (c < 18)  ? gdst + (size_t)e_n * 9 + (c - 9) :
                    (c == 18) ? gea + e_n :
                    (c < 35)  ? gu + (bl_n << 4) + (c - 19) :
                                zw;
                gl_lds4(g, &xs[(fb << 9) + (w << 6)]);
            }
        }

        // ---- layer 2: out[64, w*64:+64] = h[64,512] @ W2t^T, 16 ksteps ----
        #pragma unroll
        for (int mi = 0; mi < 4; ++mi)
            #pragma unroll
            for (int ni = 0; ni < 4; ++ni)
                acc[mi][ni] = (f32x4){0.f, 0.f, 0.f, 0.f};

        #pragma unroll 4
        for (int k0 = 0; k0 < 16; ++k0) {
            bf16x8 afr[4], bfr[4];
            const int kk = (k0 << 5) + (quad << 3);
            #pragma unroll
            for (int mi = 0; mi < 4; ++mi)
                afr[mi] = *reinterpret_cast<const bf16x8*>(
                    &hs[hidx((mi << 4) + l15, kk)]);
            #pragma unroll
            for (int ni = 0; ni < 4; ++ni)
                bfr[ni] = *reinterpret_cast<const bf16x8*>(
                    &w2p[(ni << 4) * H_SZ + (k0 << 5)]);
            #pragma unroll
            for (int mi = 0; mi < 4; ++mi)
                #pragma unroll
                for (int ni = 0; ni < 4; ++ni)
                    acc[mi][ni] = __builtin_amdgcn_mfma_f32_16x16x32_bf16(
                        afr[mi], bfr[ni], acc[mi][ni], 0, 0, 0);
        }

        // ---- epilogue: + b2, f32 store ----
        const int e0 = t * MT;
        #pragma unroll
        for (int ni = 0; ni < 4; ++ni) {
            const int col = (w << 6) + (ni << 4) + l15;
            #pragma unroll
            for (int mi = 0; mi < 4; ++mi)
                #pragma unroll
                for (int r = 0; r < 4; ++r) {
                    const int e = e0 + (mi << 4) + (quad << 2) + r;
                    if (e < E_TOTAL)
                        out[(size_t)e * OUT_SZ + col] = acc[mi][ni][r] + b2r[ni];
                }
        }
    }
}

extern "C" void kernel_launch(void* const* d_in, const int* in_sizes, int n_in,
                              void* d_out, int out_size, void* d_ws, size_t ws_size,
                              hipStream_t stream) {
    const float* src   = (const float*)d_in[0];
    const float* dst   = (const float*)d_in[1];
    const float* eattr = (const float*)d_in[2];
    const float* u     = (const float*)d_in[3];
    const int*   batch = (const int*)d_in[4];
    const float* W1    = (const float*)d_in[5];
    const float* b1    = (const float*)d_in[6];
    const float* W2    = (const float*)d_in[7];
    const float* b2    = (const float*)d_in[8];
    float* out = (float*)d_out;

    // ws layout: W2t (512*512 bf16 = 512 KB) | W1t (512*64 bf16 = 64 KB) | zero f32
    unsigned short* W2t = (unsigned short*)d_ws;
    unsigned short* W1t = W2t + H_SZ * OUT_SZ;
    float* zw = (float*)(W1t + 512 * K1);

    const int prep_total = H_SZ * OUT_SZ + 512 * K1;        // 294912
    prep_weights<<<(prep_total + 255) / 256, 256, 0, stream>>>(W1, W2, W2t, W1t, zw);

    edge_mlp<<<NB, 512, 0, stream>>>(src, dst, eattr, u, batch,
                                     b1, b2, W1t, W2t, zw, out);
}